// Round 7
// baseline (488.205 us; speedup 1.0000x reference)
//
#include <hip/hip_runtime.h>
#include <hip/hip_fp16.h>

#define D 64
#define NBMAX 512      // max buckets (nodes/256, N<=131072)
#define BCAP 5120      // per-bucket capacity; mean E/nb=4092, sigma~64 -> 16-sigma margin
#define YSTRIDE 36     // y-tile row stride in dwords (72 bf16 = 144 B, 16B-aligned)

typedef __attribute__((ext_vector_type(8))) short short8;
typedef __attribute__((ext_vector_type(4))) float float4v;

static __device__ __forceinline__ unsigned short f2bf(float x) {
    unsigned u = __float_as_uint(x);
    u += 0x7FFFu + ((u >> 16) & 1);   // RNE
    return (unsigned short)(u >> 16);
}

__global__ void zero_ints(int* __restrict__ p, int n) {
    int i = blockIdx.x * blockDim.x + threadIdx.x;
    if (i < n) p[i] = 0;
}

// x (fp32) -> xh (fp16), pre-scaled by dis[row]: s = dis[n]*x[n]
__global__ void prescale_x(const float* __restrict__ x, const float* __restrict__ dis,
                           __half* __restrict__ out, int n2) {
    int i = blockIdx.x * blockDim.x + threadIdx.x;
    if (i < n2) {
        int n = i >> 5;                 // 32 half2 per row
        float d = dis[n];
        float2 v = ((const float2*)x)[i];
        ((__half2*)out)[i] = __floats2half2_rn(v.x * d, v.y * d);
    }
}

// Bin edges into buckets of 256 consecutive dst nodes.
__global__ __launch_bounds__(256) void bucket_scatter(const int* __restrict__ src,
                                                      const int* __restrict__ dst, int E,
                                                      int nb, int* __restrict__ gcursor,
                                                      unsigned long long* __restrict__ bpair) {
    __shared__ int lhist[NBMAX];
    __shared__ int lbase[NBMAX];
    int t = threadIdx.x;
    for (int i = t; i < nb; i += 256) lhist[i] = 0;
    __syncthreads();
    int e0 = blockIdx.x * 4096, e1 = min(e0 + 4096, E);
    for (int e = e0 + t; e < e1; e += 256) atomicAdd(&lhist[dst[e] >> 8], 1);
    __syncthreads();
    for (int i = t; i < nb; i += 256) {
        int c = lhist[i];
        lbase[i] = c ? atomicAdd(&gcursor[i], c) : 0;
        lhist[i] = 0;
    }
    __syncthreads();
    for (int e = e0 + t; e < e1; e += 256) {
        int d = dst[e];
        int b = d >> 8;
        int r = lbase[b] + atomicAdd(&lhist[b], 1);
        if (r < BCAP)
            bpair[(long)b * BCAP + r] =
                ((unsigned long long)(unsigned)d << 32) | (unsigned)src[e];
    }
}

// Exclusive scan of nb (<512) bucket counts -> gbase, total at gbase[nb].
__global__ void scan_buckets(const int* __restrict__ gcursor, int B, int* __restrict__ gbase) {
    __shared__ int s[512];
    int t = threadIdx.x;
    s[t] = (t < B) ? gcursor[t] : 0;
    __syncthreads();
    for (int off = 1; off < 512; off <<= 1) {
        int v = (t >= off) ? s[t - off] : 0;
        __syncthreads();
        s[t] += v;
        __syncthreads();
    }
    if (t < B) gbase[t] = (t == 0) ? 0 : s[t - 1];
    if (t == 0) gbase[B] = s[511];
}

// One block per bucket: local histogram + scan in LDS, emit row_ptr/dis/adj_src.
__global__ __launch_bounds__(256) void bucket_build(const unsigned long long* __restrict__ bpair,
                                                    int nb, int N,
                                                    const int* __restrict__ gcursor,
                                                    const int* __restrict__ gbase,
                                                    int* __restrict__ row_ptr,
                                                    float* __restrict__ dis,
                                                    int* __restrict__ adj_src) {
    __shared__ int hist[256];
    __shared__ int cur[256];
    __shared__ int wsum[4];
    int b = blockIdx.x, t = threadIdx.x;
    int node_base = b << 8;
    int cnt = gcursor[b];
    if (cnt > BCAP) cnt = BCAP;
    int ebase = gbase[b];
    const unsigned long long* bp = bpair + (long)b * BCAP;

    hist[t] = 0;
    __syncthreads();
    for (int i = t; i < cnt; i += 256) {
        int d = (int)(bp[i] >> 32);
        atomicAdd(&hist[d - node_base], 1);
    }
    __syncthreads();
    int val = hist[t];
    int lane = t & 63, wv = t >> 6;
    int v = val;
#pragma unroll
    for (int off = 1; off < 64; off <<= 1) {
        int u = __shfl_up(v, off, 64);
        if (lane >= off) v += u;
    }
    if (lane == 63) wsum[wv] = v;
    __syncthreads();
    int wo = 0;
#pragma unroll
    for (int w = 0; w < 4; w++)
        if (w < wv) wo += wsum[w];
    int excl = wo + v - val;
    int node = node_base + t;
    if (node < N) {
        row_ptr[node] = ebase + excl;
        dis[node] = rsqrtf((float)(val + 1));  // +1 self-loop
    }
    cur[t] = ebase + excl;
    __syncthreads();
    for (int i = t; i < cnt; i += 256) {
        unsigned long long p = bp[i];
        int d = (int)(p >> 32);
        int pos = atomicAdd(&cur[d - node_base], 1);
        adj_src[pos] = (int)(p & 0xffffffffu);
    }
    if (b == 0 && t == 0) row_ptr[N] = gbase[nb];
}

// Fused GCN layer on pre-scaled storage s[n] = dis[n]*h[n]:
//   y[n] = dis[n] * ( sum_a s[a] + s[n] )
//   o    = relu(y @ W + b); store scale_out ? dis[n]*o : o
// Block = 4 waves = 64 nodes. Each wave gathers y for its 16 nodes (pair-gather,
// batched adj reads), writes bf16 y rows to its own LDS y-tile slice, then does
// its 16x64 output slice with 8x mfma_f32_16x16x32_bf16 against register-resident
// W fragments. No __syncthreads in the main path (wave reads only rows it wrote).
__global__ __launch_bounds__(256) void fused_layer(const __half* __restrict__ in,
                                                   const int* __restrict__ row_ptr,
                                                   const int* __restrict__ adj_src,
                                                   const float* __restrict__ dis,
                                                   const float* __restrict__ Wg,
                                                   const float* __restrict__ bias,
                                                   __half* __restrict__ out, int N,
                                                   int scale_out) {
    __shared__ int ytile[64 * YSTRIDE];      // 64 rows x 72 bf16 (9216 B)

    int lane = threadIdx.x & 63;
    int w = threadIdx.x >> 6;                // wave id 0..3
    int half_id = lane >> 5;
    int l31 = lane & 31;
    int col = lane & 15;                     // MFMA col / A row
    int quad = lane >> 4;                    // MFMA quad

    // Preload W fragments (B operand): B[s][c] holds W[k=32s+quad*8+j][d=16c+col]
    short8 Bf[2][4];
#pragma unroll
    for (int s = 0; s < 2; s++)
#pragma unroll
        for (int c = 0; c < 4; c++) {
            short8 f;
#pragma unroll
            for (int j = 0; j < 8; j++)
                f[j] = (short)f2bf(Wg[(32 * s + quad * 8 + j) * D + 16 * c + col]);
            Bf[s][c] = f;
        }
    float bias_c[4];
#pragma unroll
    for (int c = 0; c < 4; c++) bias_c[c] = bias[16 * c + col];

    const __half2* in2 = (const __half2*)in;   // row n starts at half2 index n*32
    int bbase = blockIdx.x * 64;
    int wbase = bbase + w * 16;                // this wave's first node
    int yrow0 = w * 16;                        // this wave's first y-tile row

    // ---- gather phase: 16 nodes, write y rows (bf16-packed) to LDS ----
    for (int i = 0; i < 16; i++) {
        int n = wbase + i;
        if (n >= N) {
            if (half_id == 0) ytile[(yrow0 + i) * YSTRIDE + l31] = 0;
            continue;
        }
        float dn = dis[n];
        int e = row_ptr[n], e_end = row_ptr[n + 1];
        float ax = 0.f, ay = 0.f;

        for (; e + 8 <= e_end; e += 8) {
            int av = adj_src[e + (lane & 7)];
#pragma unroll
            for (int j = 0; j < 4; j++) {
                int a = __shfl(av, 2 * j + half_id, 64);
                float2 r = __half22float2(in2[(long)a * 32 + l31]);
                ax += r.x;
                ay += r.y;
            }
        }
        for (; e + 2 <= e_end; e += 2) {
            int a = adj_src[e + half_id];
            float2 r = __half22float2(in2[(long)a * 32 + l31]);
            ax += r.x;
            ay += r.y;
        }
        if (e < e_end) {
            int a = adj_src[e];
            if (half_id == 0) {
                float2 r = __half22float2(in2[(long)a * 32 + l31]);
                ax += r.x;
                ay += r.y;
            }
        }
        ax += __shfl_xor(ax, 32, 64);
        ay += __shfl_xor(ay, 32, 64);

        float2 sf = __half22float2(in2[(long)n * 32 + l31]);
        float yx = dn * (ax + sf.x);
        float yy = dn * (ay + sf.y);
        if (half_id == 0)
            ytile[(yrow0 + i) * YSTRIDE + l31] =
                (int)f2bf(yx) | ((int)f2bf(yy) << 16);
    }

    // ---- MFMA phase: [16 nodes x 64 k] @ [64 k x 64 dims] ----
    // A[s]: row = col (lane&15), k = 32s + quad*8 + j  -> ds_read_b128
    short8 Af[2];
#pragma unroll
    for (int s = 0; s < 2; s++)
        Af[s] = *(const short8*)&ytile[(yrow0 + col) * YSTRIDE + 16 * s + 4 * quad];

    float4v acc[4];
#pragma unroll
    for (int c = 0; c < 4; c++) {
        float4v z = {0.f, 0.f, 0.f, 0.f};
        acc[c] = __builtin_amdgcn_mfma_f32_16x16x32_bf16(Af[0], Bf[0][c], z, 0, 0, 0);
        acc[c] = __builtin_amdgcn_mfma_f32_16x16x32_bf16(Af[1], Bf[1][c], acc[c], 0, 0, 0);
    }

    // ---- epilogue: C layout col=lane&15, row=quad*4+reg ----
    float dnv[4];
    int nodeok[4];
#pragma unroll
    for (int r = 0; r < 4; r++) {
        int node = wbase + quad * 4 + r;
        nodeok[r] = (node < N);
        dnv[r] = nodeok[r] ? (scale_out ? dis[node] : 1.f) : 0.f;
    }
#pragma unroll
    for (int c = 0; c < 4; c++) {
#pragma unroll
        for (int r = 0; r < 4; r++) {
            if (nodeok[r]) {
                int node = wbase + quad * 4 + r;
                float vv = fmaxf(acc[c][r] + bias_c[c], 0.f) * dnv[r];
                out[(long)node * D + 16 * c + col] = __float2half(vv);
            }
        }
    }
}

// Pool phase 1: grid-chunked over sorted nodes; per-wave run accumulation,
// one atomicAdd per (graph-run, lane) per wave.
__global__ __launch_bounds__(256) void pool_partial(const __half* __restrict__ h,
                                                    const int* __restrict__ batch, int N,
                                                    int chunk, float* __restrict__ pooled) {
    int lane = threadIdx.x & 63;
    int wv = threadIdx.x >> 6;
    int c0 = blockIdx.x * chunk;
    int c1 = min(c0 + chunk, N);
    int g_cur = -1;
    float acc = 0.f;
    for (int n = c0 + wv; n < c1; n += 4) {
        int g = batch[n];
        if (g != g_cur) {
            if (g_cur >= 0) atomicAdd(&pooled[g_cur * D + lane], acc);
            g_cur = g;
            acc = 0.f;
        }
        acc += __half2float(h[n * D + lane]);
    }
    if (g_cur >= 0) atomicAdd(&pooled[g_cur * D + lane], acc);
}

// Pool phase 2: one wave per graph, dot with lin_w.
__global__ void pool_linear(const float* __restrict__ pooled,
                            const float* __restrict__ lin_w,
                            const float* __restrict__ lin_b,
                            float* __restrict__ out, int G) {
    int lane = threadIdx.x & 63;
    int g = blockIdx.x * (blockDim.x >> 6) + (threadIdx.x >> 6);
    if (g >= G) return;
    float t = pooled[g * D + lane] * lin_w[lane];
#pragma unroll
    for (int off = 32; off >= 1; off >>= 1) t += __shfl_down(t, off, 64);
    if (lane == 0) out[g] = t + lin_b[0];
}

extern "C" void kernel_launch(void* const* d_in, const int* in_sizes, int n_in,
                              void* d_out, int out_size, void* d_ws, size_t ws_size,
                              hipStream_t stream) {
    const float* x      = (const float*)d_in[0];
    const int*   edges  = (const int*)d_in[1];
    const int*   batch  = (const int*)d_in[2];
    const float* W1     = (const float*)d_in[3];
    const float* b1     = (const float*)d_in[4];
    const float* W2     = (const float*)d_in[5];
    const float* b2     = (const float*)d_in[6];
    const float* W3     = (const float*)d_in[7];
    const float* b3     = (const float*)d_in[8];
    const float* lin_w  = (const float*)d_in[9];
    const float* lin_b  = (const float*)d_in[10];
    float* out = (float*)d_out;

    const int N = in_sizes[2];        // 100000
    const int E = in_sizes[1] / 2;    // 1600000
    const int G = out_size;           // 64 graphs
    const int nb = (N + 255) >> 8;    // 391 buckets of 256 nodes

    const int* e_src = edges;         // edge_index[0]
    const int* e_dst = edges + E;     // edge_index[1]

    // workspace layout (4B-element offsets, 64-elem aligned)
    auto al = [](long v) { return (v + 63) & ~63L; };
    long o_gcur   = 0;                       // NBMAX ints
    long o_pooled = al(o_gcur + NBMAX);      // G*D floats
    long o_gbase  = al(o_pooled + (long)G * D);
    long o_rowptr = al(o_gbase + nb + 1);
    long o_dis    = al(o_rowptr + N + 1);
    long o_adjs   = al(o_dis + N);
    long o_xh     = al(o_adjs + E);              // N*D halves
    long o_hA     = al(o_xh + (long)N * D / 2);  // aliases bpair (16MB < 25.6MB slot)
    long o_hB     = o_hA + (long)N * D;          // fp32-sized slots used as half buffers

    int*    gcursor = (int*)d_ws + o_gcur;
    float*  pooled  = (float*)d_ws + o_pooled;
    int*    gbase   = (int*)d_ws + o_gbase;
    int*    row_ptr = (int*)d_ws + o_rowptr;
    float*  dis     = (float*)d_ws + o_dis;
    int*    adj_src = (int*)d_ws + o_adjs;
    __half* xh      = (__half*)((float*)d_ws + o_xh);
    __half* hA      = (__half*)((float*)d_ws + o_hA);
    __half* hB      = (__half*)((float*)d_ws + o_hB);
    // bpair (nb*BCAP ulongs = 16 MB) aliases hA slot: dead before layer 2 writes hA.
    unsigned long long* bpair = (unsigned long long*)hA;

    // zero gcursor + pooled (contiguous)
    int nz = (int)(o_pooled + (long)G * D);
    zero_ints<<<(nz + 255) / 256, 256, 0, stream>>>((int*)d_ws, nz);

    // CSR build first (produces dis), then pre-scaled fp16 convert of x
    bucket_scatter<<<(E + 4095) / 4096, 256, 0, stream>>>(e_src, e_dst, E, nb, gcursor, bpair);
    scan_buckets<<<1, 512, 0, stream>>>(gcursor, nb, gbase);
    bucket_build<<<nb, 256, 0, stream>>>(bpair, nb, N, gcursor, gbase, row_ptr, dis, adj_src);

    int n2 = N * D / 2;
    prescale_x<<<(n2 + 255) / 256, 256, 0, stream>>>(x, dis, xh, n2);

    // fused GCN layers: xh -> hB -> hA -> hB
    // layers 1,2 store dis-pre-scaled output; layer 3 stores plain relu for pooling
    const int fl_blocks = (N + 63) / 64;
    fused_layer<<<fl_blocks, 256, 0, stream>>>(xh, row_ptr, adj_src, dis, W1, b1, hB, N, 1);
    fused_layer<<<fl_blocks, 256, 0, stream>>>(hB, row_ptr, adj_src, dis, W2, b2, hA, N, 1);
    fused_layer<<<fl_blocks, 256, 0, stream>>>(hA, row_ptr, adj_src, dis, W3, b3, hB, N, 0);

    // pool + final linear
    const int pool_blocks = 512;
    const int chunk = (N + pool_blocks - 1) / pool_blocks;
    pool_partial<<<pool_blocks, 256, 0, stream>>>(hB, batch, N, chunk, pooled);
    pool_linear<<<(G + 3) / 4, 256, 0, stream>>>(pooled, lin_w, lin_b, out, G);
}

// Round 8
// 418.002 us; speedup vs baseline: 1.1679x; 1.1679x over previous
//
#include <hip/hip_runtime.h>
#include <hip/hip_fp16.h>

#define D 64
#define NBMAX 512      // max buckets (nodes/256, N<=131072)
#define BCAP 5120      // per-bucket capacity; mean E/nb=4092, sigma~64 -> 16-sigma margin

static __device__ __forceinline__ float bcast_lane(float x, int k) {
    return __int_as_float(__builtin_amdgcn_readlane(__float_as_int(x), k));
}

__global__ void zero_ints(int* __restrict__ p, int n) {
    int i = blockIdx.x * blockDim.x + threadIdx.x;
    if (i < n) p[i] = 0;
}

// x (fp32) -> xh (fp16), pre-scaled by dis[row]: s = dis[n]*x[n]
__global__ void prescale_x(const float* __restrict__ x, const float* __restrict__ dis,
                           __half* __restrict__ out, int n2) {
    int i = blockIdx.x * blockDim.x + threadIdx.x;
    if (i < n2) {
        int n = i >> 5;                 // 32 half2 per row
        float d = dis[n];
        float2 v = ((const float2*)x)[i];
        ((__half2*)out)[i] = __floats2half2_rn(v.x * d, v.y * d);
    }
}

// Bin edges into buckets of 256 consecutive dst nodes.
__global__ __launch_bounds__(256) void bucket_scatter(const int* __restrict__ src,
                                                      const int* __restrict__ dst, int E,
                                                      int nb, int* __restrict__ gcursor,
                                                      unsigned long long* __restrict__ bpair) {
    __shared__ int lhist[NBMAX];
    __shared__ int lbase[NBMAX];
    int t = threadIdx.x;
    for (int i = t; i < nb; i += 256) lhist[i] = 0;
    __syncthreads();
    int e0 = blockIdx.x * 4096, e1 = min(e0 + 4096, E);
    for (int e = e0 + t; e < e1; e += 256) atomicAdd(&lhist[dst[e] >> 8], 1);
    __syncthreads();
    for (int i = t; i < nb; i += 256) {
        int c = lhist[i];
        lbase[i] = c ? atomicAdd(&gcursor[i], c) : 0;
        lhist[i] = 0;
    }
    __syncthreads();
    for (int e = e0 + t; e < e1; e += 256) {
        int d = dst[e];
        int b = d >> 8;
        int r = lbase[b] + atomicAdd(&lhist[b], 1);
        if (r < BCAP)
            bpair[(long)b * BCAP + r] =
                ((unsigned long long)(unsigned)d << 32) | (unsigned)src[e];
    }
}

// Exclusive scan of nb (<512) bucket counts -> gbase, total at gbase[nb].
__global__ void scan_buckets(const int* __restrict__ gcursor, int B, int* __restrict__ gbase) {
    __shared__ int s[512];
    int t = threadIdx.x;
    s[t] = (t < B) ? gcursor[t] : 0;
    __syncthreads();
    for (int off = 1; off < 512; off <<= 1) {
        int v = (t >= off) ? s[t - off] : 0;
        __syncthreads();
        s[t] += v;
        __syncthreads();
    }
    if (t < B) gbase[t] = (t == 0) ? 0 : s[t - 1];
    if (t == 0) gbase[B] = s[511];
}

// One block per bucket: local histogram + scan in LDS, emit row_ptr/dis/adj_src.
__global__ __launch_bounds__(256) void bucket_build(const unsigned long long* __restrict__ bpair,
                                                    int nb, int N,
                                                    const int* __restrict__ gcursor,
                                                    const int* __restrict__ gbase,
                                                    int* __restrict__ row_ptr,
                                                    float* __restrict__ dis,
                                                    int* __restrict__ adj_src) {
    __shared__ int hist[256];
    __shared__ int cur[256];
    __shared__ int wsum[4];
    int b = blockIdx.x, t = threadIdx.x;
    int node_base = b << 8;
    int cnt = gcursor[b];
    if (cnt > BCAP) cnt = BCAP;
    int ebase = gbase[b];
    const unsigned long long* bp = bpair + (long)b * BCAP;

    hist[t] = 0;
    __syncthreads();
    for (int i = t; i < cnt; i += 256) {
        int d = (int)(bp[i] >> 32);
        atomicAdd(&hist[d - node_base], 1);
    }
    __syncthreads();
    int val = hist[t];
    int lane = t & 63, wv = t >> 6;
    int v = val;
#pragma unroll
    for (int off = 1; off < 64; off <<= 1) {
        int u = __shfl_up(v, off, 64);
        if (lane >= off) v += u;
    }
    if (lane == 63) wsum[wv] = v;
    __syncthreads();
    int wo = 0;
#pragma unroll
    for (int w = 0; w < 4; w++)
        if (w < wv) wo += wsum[w];
    int excl = wo + v - val;
    int node = node_base + t;
    if (node < N) {
        row_ptr[node] = ebase + excl;
        dis[node] = rsqrtf((float)(val + 1));  // +1 self-loop
    }
    cur[t] = ebase + excl;
    __syncthreads();
    for (int i = t; i < cnt; i += 256) {
        unsigned long long p = bp[i];
        int d = (int)(p >> 32);
        int pos = atomicAdd(&cur[d - node_base], 1);
        adj_src[pos] = (int)(p & 0xffffffffu);
    }
    if (b == 0 && t == 0) row_ptr[N] = gbase[nb];
}

// Fused GCN layer on pre-scaled storage s[n] = dis[n]*h[n]:
//   y[n] = dis[n] * ( sum_a s[a] + s[n] );  o = relu(y @ W + b)
//   store scale_out ? dis[n]*o : o
// Pair-interleaved gather: each wave works nodes (n0, n0+T) with independent
// edge cursors; interleaved main loop keeps ~10 loads in flight. Epilogue
// shares each Wlds read between both nodes' fmas.
__global__ __launch_bounds__(256) void fused_layer(const __half* __restrict__ in,
                                                   const int* __restrict__ row_ptr,
                                                   const int* __restrict__ adj_src,
                                                   const float* __restrict__ dis,
                                                   const float* __restrict__ Wg,
                                                   const float* __restrict__ bias,
                                                   __half* __restrict__ out, int N,
                                                   int total_waves, int scale_out) {
    __shared__ float Wlds[D * D];
#pragma unroll
    for (int r = 0; r < 16; r++) Wlds[r * 256 + threadIdx.x] = Wg[r * 256 + threadIdx.x];
    int lane = threadIdx.x & 63;
    int half_id = lane >> 5;
    int l31 = lane & 31;
    float bl = bias[lane];
    __syncthreads();

    const __half2* in2 = (const __half2*)in;   // row n starts at half2 index n*32

    int wave = (blockIdx.x * blockDim.x + threadIdx.x) >> 6;
    for (int n0 = wave; n0 < N; n0 += 2 * total_waves) {
        int n1 = n0 + total_waves;
        bool has1 = (n1 < N);
        float dn0 = dis[n0];
        int e0 = row_ptr[n0], E0 = row_ptr[n0 + 1];
        float ax0 = 0.f, ay0 = 0.f, ax1 = 0.f, ay1 = 0.f;
        float dn1 = 0.f;
        int e1 = 0, E1 = 0;
        if (has1) { dn1 = dis[n1]; e1 = row_ptr[n1]; E1 = row_ptr[n1 + 1]; }

        // interleaved main: both nodes advance 8 edges/iter -> ~10 loads in flight
        while (e0 + 8 <= E0 && e1 + 8 <= E1) {
            int av0 = adj_src[e0 + (lane & 7)];
            int av1 = adj_src[e1 + (lane & 7)];
#pragma unroll
            for (int j = 0; j < 4; j++) {
                int a0 = __shfl(av0, 2 * j + half_id, 64);
                int a1 = __shfl(av1, 2 * j + half_id, 64);
                float2 r0 = __half22float2(in2[(long)a0 * 32 + l31]);
                float2 r1 = __half22float2(in2[(long)a1 * 32 + l31]);
                ax0 += r0.x; ay0 += r0.y;
                ax1 += r1.x; ay1 += r1.y;
            }
            e0 += 8; e1 += 8;
        }
        // drain node0
        for (; e0 + 8 <= E0; e0 += 8) {
            int av = adj_src[e0 + (lane & 7)];
#pragma unroll
            for (int j = 0; j < 4; j++) {
                int a = __shfl(av, 2 * j + half_id, 64);
                float2 r = __half22float2(in2[(long)a * 32 + l31]);
                ax0 += r.x; ay0 += r.y;
            }
        }
        for (; e0 + 2 <= E0; e0 += 2) {
            int a = adj_src[e0 + half_id];
            float2 r = __half22float2(in2[(long)a * 32 + l31]);
            ax0 += r.x; ay0 += r.y;
        }
        if (e0 < E0) {
            int a = adj_src[e0];
            if (half_id == 0) {
                float2 r = __half22float2(in2[(long)a * 32 + l31]);
                ax0 += r.x; ay0 += r.y;
            }
        }
        // drain node1
        if (has1) {
            for (; e1 + 8 <= E1; e1 += 8) {
                int av = adj_src[e1 + (lane & 7)];
#pragma unroll
                for (int j = 0; j < 4; j++) {
                    int a = __shfl(av, 2 * j + half_id, 64);
                    float2 r = __half22float2(in2[(long)a * 32 + l31]);
                    ax1 += r.x; ay1 += r.y;
                }
            }
            for (; e1 + 2 <= E1; e1 += 2) {
                int a = adj_src[e1 + half_id];
                float2 r = __half22float2(in2[(long)a * 32 + l31]);
                ax1 += r.x; ay1 += r.y;
            }
            if (e1 < E1) {
                int a = adj_src[e1];
                if (half_id == 0) {
                    float2 r = __half22float2(in2[(long)a * 32 + l31]);
                    ax1 += r.x; ay1 += r.y;
                }
            }
        }

        // combine halves
        ax0 += __shfl_xor(ax0, 32, 64);
        ay0 += __shfl_xor(ay0, 32, 64);
        ax1 += __shfl_xor(ax1, 32, 64);
        ay1 += __shfl_xor(ay1, 32, 64);

        // self-loop + dis scale: lane m holds y[2m] (x) and y[2m+1] (y)
        float2 s0 = __half22float2(in2[(long)n0 * 32 + l31]);
        float y0x = dn0 * (ax0 + s0.x);
        float y0y = dn0 * (ay0 + s0.y);
        float y1x = 0.f, y1y = 0.f;
        if (has1) {
            float2 s1 = __half22float2(in2[(long)n1 * 32 + l31]);
            y1x = dn1 * (ax1 + s1.x);
            y1y = dn1 * (ay1 + s1.y);
        }

        // epilogue: one Wlds read feeds both nodes' fmas
        float o0 = bl, o1 = bl;
#pragma unroll
        for (int m = 0; m < 32; m++) {
            float w0 = Wlds[(2 * m) * D + lane];
            float w1 = Wlds[(2 * m + 1) * D + lane];
            o0 = fmaf(bcast_lane(y0x, m), w0, o0);
            o0 = fmaf(bcast_lane(y0y, m), w1, o0);
            o1 = fmaf(bcast_lane(y1x, m), w0, o1);
            o1 = fmaf(bcast_lane(y1y, m), w1, o1);
        }
        float r0 = fmaxf(o0, 0.f);
        if (scale_out) r0 *= dn0;
        out[(long)n0 * D + lane] = __float2half(r0);
        if (has1) {
            float r1 = fmaxf(o1, 0.f);
            if (scale_out) r1 *= dn1;
            out[(long)n1 * D + lane] = __float2half(r1);
        }
    }
}

// Pool phase 1: grid-chunked over sorted nodes; per-wave run accumulation,
// one atomicAdd per (graph-run, lane) per wave.
__global__ __launch_bounds__(256) void pool_partial(const __half* __restrict__ h,
                                                    const int* __restrict__ batch, int N,
                                                    int chunk, float* __restrict__ pooled) {
    int lane = threadIdx.x & 63;
    int wv = threadIdx.x >> 6;
    int c0 = blockIdx.x * chunk;
    int c1 = min(c0 + chunk, N);
    int g_cur = -1;
    float acc = 0.f;
    for (int n = c0 + wv; n < c1; n += 4) {
        int g = batch[n];
        if (g != g_cur) {
            if (g_cur >= 0) atomicAdd(&pooled[g_cur * D + lane], acc);
            g_cur = g;
            acc = 0.f;
        }
        acc += __half2float(h[n * D + lane]);
    }
    if (g_cur >= 0) atomicAdd(&pooled[g_cur * D + lane], acc);
}

// Pool phase 2: one wave per graph, dot with lin_w.
__global__ void pool_linear(const float* __restrict__ pooled,
                            const float* __restrict__ lin_w,
                            const float* __restrict__ lin_b,
                            float* __restrict__ out, int G) {
    int lane = threadIdx.x & 63;
    int g = blockIdx.x * (blockDim.x >> 6) + (threadIdx.x >> 6);
    if (g >= G) return;
    float t = pooled[g * D + lane] * lin_w[lane];
#pragma unroll
    for (int off = 32; off >= 1; off >>= 1) t += __shfl_down(t, off, 64);
    if (lane == 0) out[g] = t + lin_b[0];
}

extern "C" void kernel_launch(void* const* d_in, const int* in_sizes, int n_in,
                              void* d_out, int out_size, void* d_ws, size_t ws_size,
                              hipStream_t stream) {
    const float* x      = (const float*)d_in[0];
    const int*   edges  = (const int*)d_in[1];
    const int*   batch  = (const int*)d_in[2];
    const float* W1     = (const float*)d_in[3];
    const float* b1     = (const float*)d_in[4];
    const float* W2     = (const float*)d_in[5];
    const float* b2     = (const float*)d_in[6];
    const float* W3     = (const float*)d_in[7];
    const float* b3     = (const float*)d_in[8];
    const float* lin_w  = (const float*)d_in[9];
    const float* lin_b  = (const float*)d_in[10];
    float* out = (float*)d_out;

    const int N = in_sizes[2];        // 100000
    const int E = in_sizes[1] / 2;    // 1600000
    const int G = out_size;           // 64 graphs
    const int nb = (N + 255) >> 8;    // 391 buckets of 256 nodes

    const int* e_src = edges;         // edge_index[0]
    const int* e_dst = edges + E;     // edge_index[1]

    // workspace layout (4B-element offsets, 64-elem aligned)
    auto al = [](long v) { return (v + 63) & ~63L; };
    long o_gcur   = 0;                       // NBMAX ints
    long o_pooled = al(o_gcur + NBMAX);      // G*D floats
    long o_gbase  = al(o_pooled + (long)G * D);
    long o_rowptr = al(o_gbase + nb + 1);
    long o_dis    = al(o_rowptr + N + 1);
    long o_adjs   = al(o_dis + N);
    long o_xh     = al(o_adjs + E);              // N*D halves
    long o_hA     = al(o_xh + (long)N * D / 2);  // aliases bpair (16MB < 25.6MB slot)
    long o_hB     = o_hA + (long)N * D;          // fp32-sized slots used as half buffers

    int*    gcursor = (int*)d_ws + o_gcur;
    float*  pooled  = (float*)d_ws + o_pooled;
    int*    gbase   = (int*)d_ws + o_gbase;
    int*    row_ptr = (int*)d_ws + o_rowptr;
    float*  dis     = (float*)d_ws + o_dis;
    int*    adj_src = (int*)d_ws + o_adjs;
    __half* xh      = (__half*)((float*)d_ws + o_xh);
    __half* hA      = (__half*)((float*)d_ws + o_hA);
    __half* hB      = (__half*)((float*)d_ws + o_hB);
    // bpair (nb*BCAP ulongs = 16 MB) aliases hA slot: dead before layer 2 writes hA.
    unsigned long long* bpair = (unsigned long long*)hA;

    // zero gcursor + pooled (contiguous)
    int nz = (int)(o_pooled + (long)G * D);
    zero_ints<<<(nz + 255) / 256, 256, 0, stream>>>((int*)d_ws, nz);

    // CSR build first (produces dis), then pre-scaled fp16 convert of x
    bucket_scatter<<<(E + 4095) / 4096, 256, 0, stream>>>(e_src, e_dst, E, nb, gcursor, bpair);
    scan_buckets<<<1, 512, 0, stream>>>(gcursor, nb, gbase);
    bucket_build<<<nb, 256, 0, stream>>>(bpair, nb, N, gcursor, gbase, row_ptr, dis, adj_src);

    int n2 = N * D / 2;
    prescale_x<<<(n2 + 255) / 256, 256, 0, stream>>>(x, dis, xh, n2);

    // fused GCN layers: xh -> hB -> hA -> hB
    // layers 1,2 store dis-pre-scaled output; layer 3 stores plain relu for pooling
    const int fl_blocks = 4096;
    const int total_waves = fl_blocks * 4;
    fused_layer<<<fl_blocks, 256, 0, stream>>>(xh, row_ptr, adj_src, dis, W1, b1, hB, N, total_waves, 1);
    fused_layer<<<fl_blocks, 256, 0, stream>>>(hB, row_ptr, adj_src, dis, W2, b2, hA, N, total_waves, 1);
    fused_layer<<<fl_blocks, 256, 0, stream>>>(hA, row_ptr, adj_src, dis, W3, b3, hB, N, total_waves, 0);

    // pool + final linear
    const int pool_blocks = 512;
    const int chunk = (N + pool_blocks - 1) / pool_blocks;
    pool_partial<<<pool_blocks, 256, 0, stream>>>(hB, batch, N, chunk, pooled);
    pool_linear<<<(G + 3) / 4, 256, 0, stream>>>(pooled, lin_w, lin_b, out, G);
}